// Round 5
// baseline (4860.528 us; speedup 1.0000x reference)
//
#include <hip/hip_runtime.h>

#define TT 50
#define BB 512
#define II 784
#define HH 800
#define OO 10
#define BH (BB*HH)   // 409600

// ---------------------------------------------------------------------------
// K1: x1 = x @ W1.T + b1 in f64 (strict ascending-k fma chain per output).
// Output stored as hi/lo f32 pair (exact to ~2^-48). PROVEN bit-exact vs ref
// (R4 first-check absmax 0). Destination pointers are plain ws arrays now.
// ---------------------------------------------------------------------------
__global__ __launch_bounds__(256) void k_gemm1(
    const float* __restrict__ x, const float* __restrict__ W1,
    const float* __restrict__ b1, float* __restrict__ x1hi,
    float* __restrict__ x1lo)
{
    __shared__ double As[16*65];
    __shared__ double Bs[16*65];
    const int m0 = blockIdx.x * 64;
    const int n0 = blockIdx.y * 64;
    const int tid = threadIdx.x;
    const int tx = tid & 15, ty = tid >> 4;
    const int sm = tid >> 2;          // 0..63 staging row
    const int sk = (tid & 3) << 2;    // 0,4,8,12 staging k
    double acc[4][4] = {{0.0}};

    const float* xrow = x + (long)(m0 + sm) * II;
    const bool bval = (n0 + sm) < HH;
    const float* wrow = W1 + (long)(n0 + sm) * II;

    for (int k0 = 0; k0 < II; k0 += 16) {   // 784 = 49*16, exact
        const float4 av = *reinterpret_cast<const float4*>(xrow + k0 + sk);
        const float4 bv = bval ? *reinterpret_cast<const float4*>(wrow + k0 + sk)
                               : make_float4(0.f, 0.f, 0.f, 0.f);
        __syncthreads();   // protect previous chunk's LDS reads
        As[(sk+0)*65 + sm] = (double)av.x;
        As[(sk+1)*65 + sm] = (double)av.y;
        As[(sk+2)*65 + sm] = (double)av.z;
        As[(sk+3)*65 + sm] = (double)av.w;
        Bs[(sk+0)*65 + sm] = (double)bv.x;
        Bs[(sk+1)*65 + sm] = (double)bv.y;
        Bs[(sk+2)*65 + sm] = (double)bv.z;
        Bs[(sk+3)*65 + sm] = (double)bv.w;
        __syncthreads();
        #pragma unroll
        for (int k = 0; k < 16; ++k) {
            double a[4], b[4];
            #pragma unroll
            for (int i = 0; i < 4; ++i) a[i] = As[k*65 + ty + 16*i];
            #pragma unroll
            for (int j = 0; j < 4; ++j) b[j] = Bs[k*65 + tx + 16*j];
            #pragma unroll
            for (int i = 0; i < 4; ++i)
                #pragma unroll
                for (int j = 0; j < 4; ++j)
                    acc[i][j] = fma(a[i], b[j], acc[i][j]);
        }
    }
    #pragma unroll
    for (int i = 0; i < 4; ++i) {
        const int m = m0 + ty + 16*i;
        #pragma unroll
        for (int j = 0; j < 4; ++j) {
            const int n = n0 + tx + 16*j;
            if (n < HH) {
                const double v = acc[i][j] + (double)b1[n];
                const float hi = (float)v;
                const float lo = (float)(v - (double)hi);
                x1hi[(long)m*HH + n] = hi;
                x1lo[(long)m*HH + n] = lo;
            }
        }
    }
}

// ---------------------------------------------------------------------------
// K2: LIF scan layer 1, f64, one thread per (b,h). Writes spike to compact
// store (ws, uchar in primary path) AND to the d_out s1r output (write-only).
// In the fallback path ST=float and s1store/s1out/x1lo alias (R4 semantics) —
// hence no __restrict__ on those three.
// ---------------------------------------------------------------------------
template <typename ST>
__global__ __launch_bounds__(256) void k_mem1(
    const float* __restrict__ x1hi, const float* x1lo,
    ST* s1store, float* s1out, const float* __restrict__ thresh1)
{
    const int lid = blockIdx.x*256 + threadIdx.x;   // = b*HH + h
    const int h = lid % HH;
    const double th = (double)thresh1[h];
    double mem = 0.0;
    for (int t = 0; t < TT; ++t) {
        const long idx = (long)t*BH + lid;
        const double xv = (double)x1hi[idx] + (double)x1lo[idx];  // read lo first
        mem = 0.95*mem + xv;
        const bool spk = mem > th;
        s1store[idx] = (ST)(spk ? 1 : 0);
        s1out[idx]   = spk ? 1.0f : 0.0f;
        if (spk) mem = 0.0;
    }
}

// ---------------------------------------------------------------------------
// K3: layer 2, strict-fp32 (PROVEN): mm = ascending-h __fmaf_rn chain; carry
// f32; ((0.95f*m)+mm)+b2, no contraction. W2 tile LDS-resident across all t;
// mem2 in registers. Spikes read from compact store; outputs written to both
// d_out s2r (write-only) and compact s2store. Row ownership tb+16i (order-
// neutral relabel; per-wave conflict-free Ss reads).
// ---------------------------------------------------------------------------
template <typename ST>
__global__ __launch_bounds__(256) void k_layer2(
    const ST* __restrict__ s1, const float* __restrict__ W2,
    const float* __restrict__ b2, const float* __restrict__ thresh2,
    float* s2out, ST* s2store)
{
    __shared__ float W2s[16][820];
    __shared__ float Ss[64][44];
    const int n0 = (blockIdx.x % 50) * 16;
    const int b0 = (blockIdx.x / 50) * 64;
    const int tid = threadIdx.x;
    const int tn = tid & 15;        // n within tile
    const int tb = tid >> 4;        // 0..15, owns b rows tb, tb+16, tb+32, tb+48

    // stage W2 tile once (reused across all 50 timesteps)
    {
        const int r  = tid >> 4;          // 0..15
        const int j0 = (tid & 15) * 50;   // 0..750
        const float* src = W2 + (long)(n0 + r) * HH + j0;
        for (int j = 0; j < 50; ++j) W2s[r][j0 + j] = src[j];
    }
    const float b2v = b2[n0 + tn];
    const float thv = thresh2[n0 + tn];
    float m[4] = {0.0f, 0.0f, 0.0f, 0.0f};
    __syncthreads();

    const int r2 = tid >> 2;            // 0..63 staging row
    const int cj = tid & 3;             // staging col group
    for (int t = 0; t < TT; ++t) {
        float mm[4] = {0.0f, 0.0f, 0.0f, 0.0f};
        for (int c = 0; c < 20; ++c) {  // 20 chunks of 40 h
            {
                const ST* src = s1 + (long)t*BH + (long)(b0 + r2)*HH + c*40;
                #pragma unroll
                for (int j = 0; j < 10; ++j)
                    Ss[r2][cj + 4*j] = (float)src[cj + 4*j];
            }
            __syncthreads();
            #pragma unroll
            for (int k4 = 0; k4 < 10; ++k4) {
                const float4 w4 = *reinterpret_cast<const float4*>(
                    &W2s[tn][c*40 + k4*4]);
                #pragma unroll
                for (int i = 0; i < 4; ++i) {
                    const float4 s4 = *reinterpret_cast<const float4*>(
                        &Ss[tb + 16*i][k4*4]);
                    mm[i] = __fmaf_rn(s4.x, w4.x, mm[i]);
                    mm[i] = __fmaf_rn(s4.y, w4.y, mm[i]);
                    mm[i] = __fmaf_rn(s4.z, w4.z, mm[i]);
                    mm[i] = __fmaf_rn(s4.w, w4.w, mm[i]);
                }
            }
            __syncthreads();
        }
        #pragma unroll
        for (int i = 0; i < 4; ++i) {
            const int bg = b0 + tb + 16*i;
            const float m2 = __fadd_rn(
                __fadd_rn(__fmul_rn(0.95f, m[i]), mm[i]), b2v);
            const bool spk = m2 > thv;
            const long idx = (long)t*BH + (long)bg*HH + n0 + tn;
            s2out[idx]   = spk ? 1.0f : 0.0f;
            s2store[idx] = (ST)(spk ? 1 : 0);
            m[i] = spk ? 0.0f : m2;
        }
    }
}

// ---------------------------------------------------------------------------
// K4: layer 3, strict-fp32 single ascending-h chain (PROVEN). Reads compact
// spike store; d_out writes only.
// ---------------------------------------------------------------------------
template <typename ST>
__global__ __launch_bounds__(256) void k_layer3(
    const ST* __restrict__ s2, const float* __restrict__ W3,
    const float* __restrict__ b3, float* __restrict__ s3r,
    float* __restrict__ out0)
{
    const int gid = blockIdx.x*256 + threadIdx.x;
    if (gid >= BB*OO) return;
    const int b = gid / OO, o = gid % OO;
    const float* w = W3 + (long)o*HH;
    const float b3v = b3[o];
    float mem = 0.0f, cnt = 0.0f;
    for (int t = 0; t < TT; ++t) {
        const ST* s2p = s2 + (long)t*BH + (long)b*HH;
        float acc = 0.0f;                       // strict ascending chain
        for (int h = 0; h < HH; ++h)
            acc = __fmaf_rn((float)s2p[h], w[h], acc);
        const float m3 = __fadd_rn(
            __fadd_rn(__fmul_rn(0.95f, mem), acc), b3v);
        const bool spk = m3 > 1.0f;
        s3r[(long)t*BB*OO + gid] = spk ? 1.0f : 0.0f;
        if (spk) cnt = __fadd_rn(cnt, 1.0f);
        mem = spk ? 0.0f : m3;
    }
    out0[gid] = cnt;
}

// ---------------------------------------------------------------------------
extern "C" void kernel_launch(void* const* d_in, const int* in_sizes, int n_in,
                              void* d_out, int out_size, void* d_ws, size_t ws_size,
                              hipStream_t stream)
{
    const float* x   = (const float*)d_in[0];
    const float* W1  = (const float*)d_in[1];
    const float* b1  = (const float*)d_in[2];
    const float* W2  = (const float*)d_in[3];
    const float* b2  = (const float*)d_in[4];
    const float* W3  = (const float*)d_in[5];
    const float* b3  = (const float*)d_in[6];
    const float* th1 = (const float*)d_in[7];
    const float* th2 = (const float*)d_in[8];

    float* out0 = (float*)d_out;                    // (B, OUT)
    float* s1r  = out0 + BB*OO;                     // (T, B, H)
    float* s2r  = s1r + (long)TT*BH;                // (T, B, H)
    float* s3r  = s2r + (long)TT*BH;                // (T, B, OUT)

    const size_t nx1 = (size_t)TT * BH;             // 20,480,000
    const bool ws_ok = ws_size >= nx1*4*2 + nx1*2;  // 204.8 MB (R1 proved >=219)

    if (ws_ok) {
        // Primary: d_out is WRITE-ONLY; all intermediates live in ws.
        float* x1hi = (float*)d_ws;
        float* x1lo = x1hi + nx1;
        unsigned char* s1c = (unsigned char*)(x1lo + nx1);
        unsigned char* s2c = s1c + nx1;
        k_gemm1<<<dim3(400,13), dim3(256), 0, stream>>>(x, W1, b1, x1hi, x1lo);
        k_mem1<unsigned char><<<dim3(1600), dim3(256), 0, stream>>>(
            x1hi, x1lo, s1c, s1r, th1);
        k_layer2<unsigned char><<<dim3(400), dim3(256), 0, stream>>>(
            s1c, W2, b2, th2, s2r, s2c);
        k_layer3<unsigned char><<<dim3(20), dim3(256), 0, stream>>>(
            s2c, W3, b3, s3r, out0);
    } else {
        // Fallback (statically chosen, same every call): R4 d_out-scratch scheme.
        float* x1hi = s2r;
        float* x1lo = s1r;
        k_gemm1<<<dim3(400,13), dim3(256), 0, stream>>>(x, W1, b1, x1hi, x1lo);
        k_mem1<float><<<dim3(1600), dim3(256), 0, stream>>>(
            x1hi, x1lo, s1r, s1r, th1);
        k_layer2<float><<<dim3(400), dim3(256), 0, stream>>>(
            s1r, W2, b2, th2, s2r, s2r);
        k_layer3<float><<<dim3(20), dim3(256), 0, stream>>>(
            s2r, W3, b3, s3r, out0);
    }
}

// Round 6
// 1481.466 us; speedup vs baseline: 3.2809x; 3.2809x over previous
//
#include <hip/hip_runtime.h>

#define TT 50
#define BB 512
#define II 784
#define HH 800
#define OO 10
#define BH (BB*HH)   // 409600
#define MM (TT*BB)   // 25600

// ---------------------------------------------------------------------------
// K1: x1d[m][n] = sum_k x[m][k]*W1[n][k] + b1[n], all f64 (order-safe: R1/R3
// proved any f64 order matches ref's layer-1 exactly).
// M=25600, N=800, K=784. Tile 128m x 80n, KC=16, frag 8m x 5n strided
// (m = ty+16i, n = tx+16j -> broadcast/conflict-free LDS reads).
// Grid 200 x 10 = 2000 blocks.
// ---------------------------------------------------------------------------
__global__ __launch_bounds__(256) void k_gemm1(
    const float* __restrict__ x, const float* __restrict__ W1,
    const float* __restrict__ b1, double* __restrict__ x1d)
{
    __shared__ double As[16*130];
    __shared__ double Bs[16*82];
    const int m0 = blockIdx.x * 128;
    const int n0 = blockIdx.y * 80;
    const int tid = threadIdx.x;
    const int tx = tid & 15, ty = tid >> 4;
    double acc[8][5] = {};

    const int sm = tid >> 1;          // 0..127  A staging row
    const int sk = (tid & 1) * 8;     // 0 or 8  A staging k-offset
    const int bq0n = tid >> 2, bq0k = (tid & 3) * 4;          // B task 0
    const int q1 = tid + 256;
    const int bq1n = q1 >> 2, bq1k = (q1 & 3) * 4;            // B task 1 (tid<64)

    for (int k0 = 0; k0 < II; k0 += 16) {   // 784 = 49*16
        const float4 a0 = *(const float4*)(x + (long)(m0+sm)*II + k0 + sk);
        const float4 a1 = *(const float4*)(x + (long)(m0+sm)*II + k0 + sk + 4);
        const float4 bv0 = *(const float4*)(W1 + (long)(n0+bq0n)*II + k0 + bq0k);
        float4 bv1;
        if (tid < 64)
            bv1 = *(const float4*)(W1 + (long)(n0+bq1n)*II + k0 + bq1k);
        __syncthreads();   // protect previous chunk's reads
        As[(sk+0)*130+sm] = (double)a0.x;
        As[(sk+1)*130+sm] = (double)a0.y;
        As[(sk+2)*130+sm] = (double)a0.z;
        As[(sk+3)*130+sm] = (double)a0.w;
        As[(sk+4)*130+sm] = (double)a1.x;
        As[(sk+5)*130+sm] = (double)a1.y;
        As[(sk+6)*130+sm] = (double)a1.z;
        As[(sk+7)*130+sm] = (double)a1.w;
        Bs[(bq0k+0)*82+bq0n] = (double)bv0.x;
        Bs[(bq0k+1)*82+bq0n] = (double)bv0.y;
        Bs[(bq0k+2)*82+bq0n] = (double)bv0.z;
        Bs[(bq0k+3)*82+bq0n] = (double)bv0.w;
        if (tid < 64) {
            Bs[(bq1k+0)*82+bq1n] = (double)bv1.x;
            Bs[(bq1k+1)*82+bq1n] = (double)bv1.y;
            Bs[(bq1k+2)*82+bq1n] = (double)bv1.z;
            Bs[(bq1k+3)*82+bq1n] = (double)bv1.w;
        }
        __syncthreads();
        #pragma unroll
        for (int k = 0; k < 16; ++k) {
            double a[8], b[5];
            #pragma unroll
            for (int i = 0; i < 8; ++i) a[i] = As[k*130 + ty + 16*i];
            #pragma unroll
            for (int j = 0; j < 5; ++j) b[j] = Bs[k*82 + tx + 16*j];
            #pragma unroll
            for (int i = 0; i < 8; ++i)
                #pragma unroll
                for (int j = 0; j < 5; ++j)
                    acc[i][j] = fma(a[i], b[j], acc[i][j]);
        }
    }
    #pragma unroll
    for (int i = 0; i < 8; ++i) {
        const long m = m0 + ty + 16*i;
        #pragma unroll
        for (int j = 0; j < 5; ++j) {
            const int n = n0 + tx + 16*j;
            x1d[m*HH + n] = acc[i][j] + (double)b1[n];
        }
    }
}

// ---------------------------------------------------------------------------
// K2: LIF scan layer 1, f64 (PROVEN path). Reads x1d; writes compact u8
// spikes (ws) + s1r f32 (d_out, write-only).
// ---------------------------------------------------------------------------
__global__ __launch_bounds__(256) void k_mem1(
    const double* __restrict__ x1d, const float* __restrict__ thresh1,
    unsigned char* __restrict__ s1c, float* __restrict__ s1r)
{
    const int lid = blockIdx.x*256 + threadIdx.x;   // = b*HH + h
    const int h = lid % HH;
    const double th = (double)thresh1[h];
    double mem = 0.0;
    for (int t = 0; t < TT; ++t) {
        const long idx = (long)t*BH + lid;
        mem = 0.95*mem + x1d[idx];
        const bool spk = mem > th;
        s1c[idx] = spk ? 1 : 0;
        s1r[idx] = spk ? 1.0f : 0.0f;
        if (spk) mem = 0.0;
    }
}

// ---------------------------------------------------------------------------
// K3: z2[m][n] = chain_k( s1[m][k]*W2[n][k] ) — strict ascending-k single
// __fmaf_rn chain per output (EXACT R5 layer-2 semantics; u8->f32 is exact).
// Tile 128m x 80n, KC=32, frag 8m(contig) x (4n contig + 1), grid 200x10.
// ---------------------------------------------------------------------------
__global__ __launch_bounds__(256) void k_gemm2(
    const unsigned char* __restrict__ s1c, const float* __restrict__ W2,
    float* __restrict__ z2)
{
    __shared__ float As[32*132];
    __shared__ float Bs[32*84];
    const int m0 = blockIdx.x * 128;
    const int n0 = blockIdx.y * 80;
    const int tid = threadIdx.x;
    const int tx = tid & 15, ty = tid >> 4;
    float acc[8][5] = {};

    const int sm = tid >> 1;          // 0..127
    const int sk = (tid & 1) * 16;    // 0 or 16
    // B: 80 rows x 32 k = 640 float4 tasks: tid, tid+256, tid+512(<128)
    const int b0n = tid >> 3,        b0k = (tid & 7) * 4;
    const int q1 = tid + 256, b1n = q1 >> 3, b1k = (q1 & 7) * 4;
    const int q2 = tid + 512, b2n = q2 >> 3, b2k = (q2 & 7) * 4;

    for (int k0 = 0; k0 < HH; k0 += 32) {   // 800 = 25*32
        const uint4 av = *(const uint4*)(s1c + (long)(m0+sm)*HH + k0 + sk);
        const float4 w0 = *(const float4*)(W2 + (long)(n0+b0n)*HH + k0 + b0k);
        const float4 w1 = *(const float4*)(W2 + (long)(n0+b1n)*HH + k0 + b1k);
        float4 w2;
        if (tid < 128)
            w2 = *(const float4*)(W2 + (long)(n0+b2n)*HH + k0 + b2k);
        __syncthreads();
        {
            const unsigned int d[4] = {av.x, av.y, av.z, av.w};
            #pragma unroll
            for (int w = 0; w < 4; ++w) {
                #pragma unroll
                for (int j = 0; j < 4; ++j)
                    As[(sk + w*4 + j)*132 + sm] =
                        (float)((d[w] >> (8*j)) & 0xffu);
            }
        }
        Bs[(b0k+0)*84+b0n] = w0.x; Bs[(b0k+1)*84+b0n] = w0.y;
        Bs[(b0k+2)*84+b0n] = w0.z; Bs[(b0k+3)*84+b0n] = w0.w;
        Bs[(b1k+0)*84+b1n] = w1.x; Bs[(b1k+1)*84+b1n] = w1.y;
        Bs[(b1k+2)*84+b1n] = w1.z; Bs[(b1k+3)*84+b1n] = w1.w;
        if (tid < 128) {
            Bs[(b2k+0)*84+b2n] = w2.x; Bs[(b2k+1)*84+b2n] = w2.y;
            Bs[(b2k+2)*84+b2n] = w2.z; Bs[(b2k+3)*84+b2n] = w2.w;
        }
        __syncthreads();
        #pragma unroll
        for (int k = 0; k < 32; ++k) {
            float a[8], b[5];
            #pragma unroll
            for (int i = 0; i < 8; ++i) a[i] = As[k*132 + ty*8 + i];
            #pragma unroll
            for (int j = 0; j < 4; ++j) b[j] = Bs[k*84 + tx*4 + j];
            b[4] = Bs[k*84 + 64 + tx];
            #pragma unroll
            for (int i = 0; i < 8; ++i)
                #pragma unroll
                for (int j = 0; j < 5; ++j)
                    acc[i][j] = __fmaf_rn(a[i], b[j], acc[i][j]);
        }
    }
    #pragma unroll
    for (int i = 0; i < 8; ++i) {
        const long m = m0 + ty*8 + i;
        #pragma unroll
        for (int j = 0; j < 4; ++j)
            z2[m*HH + n0 + tx*4 + j] = acc[i][j];
        z2[m*HH + n0 + 64 + tx] = acc[i][4];
    }
}

// ---------------------------------------------------------------------------
// K4: layer-2 membrane scan, strict fp32 np order ((0.95f*m)+z)+b2 (EXACT
// R5 semantics). mem2 in registers; writes s2r (d_out) + s2c (ws u8).
// ---------------------------------------------------------------------------
__global__ __launch_bounds__(256) void k_scan2(
    const float* __restrict__ z2, const float* __restrict__ b2,
    const float* __restrict__ thresh2, float* __restrict__ s2r,
    unsigned char* __restrict__ s2c)
{
    const int lid = blockIdx.x*256 + threadIdx.x;   // = b*HH + n
    const int n = lid % HH;
    const float b2v = b2[n];
    const float thv = thresh2[n];
    float m = 0.0f;
    for (int t = 0; t < TT; ++t) {
        const long idx = (long)t*BH + lid;
        const float m2 = __fadd_rn(
            __fadd_rn(__fmul_rn(0.95f, m), z2[idx]), b2v);
        const bool spk = m2 > thv;
        s2r[idx] = spk ? 1.0f : 0.0f;
        s2c[idx] = spk ? 1 : 0;
        m = spk ? 0.0f : m2;
    }
}

// ---------------------------------------------------------------------------
// K5: z3[m][o] = chain_k( s2[m][k]*W3[o][k] ) — strict ascending-k single
// chain (EXACT R5 layer-3 matmul semantics). One thread per m row, 10 accs;
// W3 accesses are wave-uniform -> scalar loads.
// ---------------------------------------------------------------------------
__global__ __launch_bounds__(256) void k_gemm3(
    const unsigned char* __restrict__ s2c, const float* __restrict__ W3,
    float* __restrict__ z3)
{
    const long m = blockIdx.x*256 + threadIdx.x;
    const unsigned char* row = s2c + m*HH;
    float acc[10] = {};
    for (int k0 = 0; k0 < HH; k0 += 16) {
        const uint4 v = *(const uint4*)(row + k0);
        const unsigned int d[4] = {v.x, v.y, v.z, v.w};
        #pragma unroll
        for (int w = 0; w < 4; ++w) {
            #pragma unroll
            for (int j = 0; j < 4; ++j) {
                const float sv = (float)((d[w] >> (8*j)) & 0xffu);
                const int k = k0 + w*4 + j;
                #pragma unroll
                for (int o = 0; o < 10; ++o)
                    acc[o] = __fmaf_rn(sv, W3[o*HH + k], acc[o]);
            }
        }
    }
    #pragma unroll
    for (int o = 0; o < 10; ++o)
        z3[m*OO + o] = acc[o];
}

// ---------------------------------------------------------------------------
// K6: layer-3 membrane scan, strict fp32 (EXACT R5 semantics). Writes s3r +
// out0 (d_out, write-only).
// ---------------------------------------------------------------------------
__global__ __launch_bounds__(256) void k_scan3(
    const float* __restrict__ z3, const float* __restrict__ b3,
    float* __restrict__ s3r, float* __restrict__ out0)
{
    const int gid = blockIdx.x*256 + threadIdx.x;   // = b*OO + o
    if (gid >= BB*OO) return;
    const int o = gid % OO;
    const float b3v = b3[o];
    float mem = 0.0f, cnt = 0.0f;
    for (int t = 0; t < TT; ++t) {
        const float m3 = __fadd_rn(
            __fadd_rn(__fmul_rn(0.95f, mem), z3[(long)t*BB*OO + gid]), b3v);
        const bool spk = m3 > 1.0f;
        s3r[(long)t*BB*OO + gid] = spk ? 1.0f : 0.0f;
        if (spk) cnt = __fadd_rn(cnt, 1.0f);
        mem = spk ? 0.0f : m3;
    }
    out0[gid] = cnt;
}

// ---------------------------------------------------------------------------
extern "C" void kernel_launch(void* const* d_in, const int* in_sizes, int n_in,
                              void* d_out, int out_size, void* d_ws, size_t ws_size,
                              hipStream_t stream)
{
    const float* x   = (const float*)d_in[0];
    const float* W1  = (const float*)d_in[1];
    const float* b1  = (const float*)d_in[2];
    const float* W2  = (const float*)d_in[3];
    const float* b2  = (const float*)d_in[4];
    const float* W3  = (const float*)d_in[5];
    const float* b3  = (const float*)d_in[6];
    const float* th1 = (const float*)d_in[7];
    const float* th2 = (const float*)d_in[8];

    float* out0 = (float*)d_out;                    // (B, OUT)   d_out is
    float* s1r  = out0 + BB*OO;                     // (T, B, H)  WRITE-ONLY
    float* s2r  = s1r + (long)TT*BH;                // (T, B, H)
    float* s3r  = s2r + (long)TT*BH;                // (T, B, OUT)

    // ws layout (total 204.8 MB == R5-proven budget):
    //   [0 .. 163.84 MB)   x1d f64  — dead after k_mem1, region reused:
    //        [0 .. 81.92 MB)      z2 f32  (written by k_gemm2 after k_mem1)
    //        [84 MB .. 85.03 MB)  z3 f32
    //   [163.84 .. 184.32 MB) s1c u8
    //   [184.32 .. 204.80 MB) s2c u8
    char* p = (char*)d_ws;
    double* x1d = (double*)p;
    float*  z2  = (float*)p;
    float*  z3  = (float*)(p + 84000000);
    unsigned char* s1c = (unsigned char*)(p + 163840000);
    unsigned char* s2c = s1c + (size_t)TT*BH;
    (void)ws_size;

    k_gemm1<<<dim3(200,10), dim3(256), 0, stream>>>(x, W1, b1, x1d);
    k_mem1 <<<dim3(1600),   dim3(256), 0, stream>>>(x1d, th1, s1c, s1r);
    k_gemm2<<<dim3(200,10), dim3(256), 0, stream>>>(s1c, W2, z2);
    k_scan2<<<dim3(1600),   dim3(256), 0, stream>>>(z2, b2, th2, s2r, s2c);
    k_gemm3<<<dim3(100),    dim3(256), 0, stream>>>(s2c, W3, z3);
    k_scan3<<<dim3(20),     dim3(256), 0, stream>>>(z3, b3, s3r, out0);
}